// Round 9
// baseline (39.772 us; speedup 1.0000x reference)
//
#include <hip/hip_runtime.h>
#include <math.h>

// SPD logm -> 2x2 avg-pool -> expm via matrix polynomials on fp16 MFMA.
// Round 9: ONE WAVE PER MATRIX. A 64-lane wave owns the whole 64x64 chain:
//  - symmetric operands => B-fragment set == A-fragment set (row-slices),
//    so each 64^3 matmul needs only 8 ds_read_b128 (no cross-wave duplicates)
//  - ZERO barriers: same-wave DS ops are in-order; Z->Q is an in-place
//    overwrite at the same transposed addresses; r(Z) stays in the
//    accumulators as mm3's C-init.
//  - LDS 16 KB/wave -> ~10 resident waves/CU; launch_bounds(64,4) caps VGPR.
// Math identical to rounds 5-8: p(T) = T*q(Z) + r(Z), Z = T^2, degree-5
// Chebyshev logm on [1,6]; degree-5 Taylor expm. (absmax floor 0.0078.)

typedef __attribute__((ext_vector_type(8))) _Float16 f16x8;
typedef __attribute__((ext_vector_type(4))) _Float16 f16x4;
typedef __attribute__((ext_vector_type(2))) _Float16 f16x2;
typedef __attribute__((ext_vector_type(4))) float f32x4;

struct Coeffs {
  float b[6];  // logm monomial coeffs (degree 5), Chebyshev fit on [1,6]
  float c[6];  // expm Taylor 1/k!
};

// byte offset of (r,c): 64x64 f16, 128B rows, 16B-granule XOR swizzle
__device__ __forceinline__ int swz64(int r, int c) {
  return r * 128 + ((((c >> 3) ^ r) & 7) << 4) + ((c & 7) << 1);
}
// 32x32 f16, 64B rows, 4 granules
__device__ __forceinline__ int swz32(int r, int c) {
  return r * 64 + ((((c >> 3) ^ r) & 3) << 4) + ((c & 7) << 1);
}

__device__ __forceinline__ f16x4 cvt4(float a, float b, float c, float d) {
  f16x4 v;
  v[0] = (_Float16)a; v[1] = (_Float16)b; v[2] = (_Float16)c; v[3] = (_Float16)d;
  return v;
}

__global__ __launch_bounds__(64, 4) void spd_wave_kernel(
    const float* __restrict__ A, float* __restrict__ out, Coeffs co) {
  __shared__ __align__(16) char smem[16384];
  char* TB = smem;           // 64x64 f16 T                  (8 KB)
  char* ZQ = smem + 8192;    // Z = T^2, overwritten by Q    (8 KB)
  // expm overlays inside ZQ (all Q-frag reads precede these writes in
  // program order; same-wave DS ops are in-order)
  char* PB  = ZQ;            // 32x32 pooled P (2 KB)
  char* ZeB = ZQ + 2048;     // Ze = P^2 f16 frags (2 KB)
  char* QeB = ZQ + 4096;     // Qe frags (2 KB)

  const int l = threadIdx.x;     // 0..63 (one wave)
  const int lm = l & 15;
  const int lg = l >> 4;
  const float4* __restrict__ Ap = (const float4*)(A + (size_t)blockIdx.x * 4096);
  float* __restrict__ Om = out + (size_t)blockIdx.x * 1024;

  // ---- Phase 0: T = (A - 3.5 I)/2.5 -> f16 swizzled (coalesced 1KB/instr) ----
  {
    const float invh = 0.4f;
#pragma unroll
    for (int ch = 0; ch < 16; ++ch) {
      const float4 v = Ap[(ch << 6) + l];
      const int row = (ch << 2) + lg;
      const int col0 = lm << 2;
      f16x4 t;
      t[0] = (_Float16)((v.x - (row == col0 + 0 ? 3.5f : 0.0f)) * invh);
      t[1] = (_Float16)((v.y - (row == col0 + 1 ? 3.5f : 0.0f)) * invh);
      t[2] = (_Float16)((v.z - (row == col0 + 2 ? 3.5f : 0.0f)) * invh);
      t[3] = (_Float16)((v.w - (row == col0 + 3 ? 3.5f : 0.0f)) * invh);
      *(f16x4*)(TB + swz64(row, col0)) = t;
    }
  }

  f32x4 acc[4][4];

  // ---- mm1: Z = T*T  (8 frag reads total; frags serve as A AND B) ----
#pragma unroll
  for (int i = 0; i < 4; ++i)
#pragma unroll
    for (int j = 0; j < 4; ++j) acc[i][j] = f32x4{0.f, 0.f, 0.f, 0.f};
#pragma unroll
  for (int kh = 0; kh < 2; ++kh) {
    f16x8 f0 = *(const f16x8*)(TB + swz64((0 << 4) + lm, (kh << 5) + (lg << 3)));
    f16x8 f1 = *(const f16x8*)(TB + swz64((1 << 4) + lm, (kh << 5) + (lg << 3)));
    f16x8 f2 = *(const f16x8*)(TB + swz64((2 << 4) + lm, (kh << 5) + (lg << 3)));
    f16x8 f3 = *(const f16x8*)(TB + swz64((3 << 4) + lm, (kh << 5) + (lg << 3)));
    f16x8 f[4] = {f0, f1, f2, f3};
#pragma unroll
    for (int rb = 0; rb < 4; ++rb)
#pragma unroll
      for (int cb = 0; cb < 4; ++cb)
        acc[rb][cb] = __builtin_amdgcn_mfma_f32_16x16x32_f16(f[rb], f[cb], acc[rb][cb], 0, 0, 0);
  }
  // epilogue: write Z f16 at transposed positions (symmetric)
#pragma unroll
  for (int ti = 0; ti < 4; ++ti)
#pragma unroll
    for (int tj = 0; tj < 4; ++tj) {
      const int colB = (tj << 4) + lm;
      const int row0 = (ti << 4) + (lg << 2);
      *(f16x4*)(ZQ + swz64(colB, row0)) =
          cvt4(acc[ti][tj][0], acc[ti][tj][1], acc[ti][tj][2], acc[ti][tj][3]);
    }

  // ---- mm2: Z2 = Z*Z ; then in-place Q = b5 Z2 + b3 Z + b1 I,
  //      RP = b4 Z2 + b2 Z + b0 I kept in acc as mm3's C-init ----
  f32x4 a2[4][4];
#pragma unroll
  for (int i = 0; i < 4; ++i)
#pragma unroll
    for (int j = 0; j < 4; ++j) a2[i][j] = f32x4{0.f, 0.f, 0.f, 0.f};
#pragma unroll
  for (int kh = 0; kh < 2; ++kh) {
    f16x8 f0 = *(const f16x8*)(ZQ + swz64((0 << 4) + lm, (kh << 5) + (lg << 3)));
    f16x8 f1 = *(const f16x8*)(ZQ + swz64((1 << 4) + lm, (kh << 5) + (lg << 3)));
    f16x8 f2 = *(const f16x8*)(ZQ + swz64((2 << 4) + lm, (kh << 5) + (lg << 3)));
    f16x8 f3 = *(const f16x8*)(ZQ + swz64((3 << 4) + lm, (kh << 5) + (lg << 3)));
    f16x8 f[4] = {f0, f1, f2, f3};
#pragma unroll
    for (int rb = 0; rb < 4; ++rb)
#pragma unroll
      for (int cb = 0; cb < 4; ++cb)
        a2[rb][cb] = __builtin_amdgcn_mfma_f32_16x16x32_f16(f[rb], f[cb], a2[rb][cb], 0, 0, 0);
  }
#pragma unroll
  for (int ti = 0; ti < 4; ++ti)
#pragma unroll
    for (int tj = 0; tj < 4; ++tj) {
      const int colB = (tj << 4) + lm;
      const int row0 = (ti << 4) + (lg << 2);
      const int off = swz64(colB, row0);
      const f16x4 zr = *(const f16x4*)(ZQ + off);  // Z readback (f16)
      f16x4 q;
      f32x4 rp;
#pragma unroll
      for (int r = 0; r < 4; ++r) {
        const float zv = (float)zr[r];
        const bool dg = (ti == tj) && (((lg << 2) + r) == lm);
        q[r] = (_Float16)fmaf(co.b[5], a2[ti][tj][r],
                              fmaf(co.b[3], zv, dg ? co.b[1] : 0.0f));
        rp[r] = fmaf(co.b[4], a2[ti][tj][r],
                     fmaf(co.b[2], zv, dg ? co.b[0] : 0.0f));
      }
      a2[ti][tj] = rp;               // C-init for mm3
      *(f16x4*)(ZQ + off) = q;       // in-place Z -> Q
    }

  // ---- mm3: L = T*Q + RP ; fused 2x2 pooling -> P (f16, overlays ZQ) ----
#pragma unroll
  for (int kh = 0; kh < 2; ++kh) {
    f16x8 fT[4], fQ[4];
#pragma unroll
    for (int rb = 0; rb < 4; ++rb) {
      fT[rb] = *(const f16x8*)(TB + swz64((rb << 4) + lm, (kh << 5) + (lg << 3)));
      fQ[rb] = *(const f16x8*)(ZQ + swz64((rb << 4) + lm, (kh << 5) + (lg << 3)));
    }
#pragma unroll
    for (int rb = 0; rb < 4; ++rb)
#pragma unroll
      for (int cb = 0; cb < 4; ++cb)
        a2[rb][cb] = __builtin_amdgcn_mfma_f32_16x16x32_f16(fT[rb], fQ[cb], a2[rb][cb], 0, 0, 0);
  }
#pragma unroll
  for (int ti = 0; ti < 4; ++ti)
#pragma unroll
    for (int tj = 0; tj < 4; ++tj) {
      const float vs0 = a2[ti][tj][0] + a2[ti][tj][1];
      const float vs1 = a2[ti][tj][2] + a2[ti][tj][3];
      const float hs0 = vs0 + __shfl_xor(vs0, 1);
      const float hs1 = vs1 + __shfl_xor(vs1, 1);
      if ((lm & 1) == 0) {
        const int pr = (ti << 3) + (lg << 1);
        const int pc = (tj << 3) + (lm >> 1);
        f16x2 p;
        p[0] = (_Float16)(0.25f * hs0);
        p[1] = (_Float16)(0.25f * hs1);
        *(f16x2*)(PB + swz32(pc, pr)) = p;  // transposed (symmetric)
      }
    }

  // ---- expm on 32x32 P, still one wave (2x2 tiles) ----
  f32x4 eZ[2][2];
#pragma unroll
  for (int i = 0; i < 2; ++i)
#pragma unroll
    for (int j = 0; j < 2; ++j) eZ[i][j] = f32x4{0.f, 0.f, 0.f, 0.f};
  {
    f16x8 fp[2];
#pragma unroll
    for (int rb = 0; rb < 2; ++rb)
      fp[rb] = *(const f16x8*)(PB + swz32((rb << 4) + lm, lg << 3));
#pragma unroll
    for (int rb = 0; rb < 2; ++rb)
#pragma unroll
      for (int cb = 0; cb < 2; ++cb)
        eZ[rb][cb] = __builtin_amdgcn_mfma_f32_16x16x32_f16(fp[rb], fp[cb], eZ[rb][cb], 0, 0, 0);
  }
  // write Ze frags (transposed)
#pragma unroll
  for (int ti = 0; ti < 2; ++ti)
#pragma unroll
    for (int tj = 0; tj < 2; ++tj) {
      const int off = swz32((tj << 4) + lm, (ti << 4) + (lg << 2));
      *(f16x4*)(ZeB + off) = cvt4(eZ[ti][tj][0], eZ[ti][tj][1], eZ[ti][tj][2], eZ[ti][tj][3]);
    }

  f32x4 e2[2][2];
#pragma unroll
  for (int i = 0; i < 2; ++i)
#pragma unroll
    for (int j = 0; j < 2; ++j) e2[i][j] = f32x4{0.f, 0.f, 0.f, 0.f};
  {
    f16x8 fz[2];
#pragma unroll
    for (int rb = 0; rb < 2; ++rb)
      fz[rb] = *(const f16x8*)(ZeB + swz32((rb << 4) + lm, lg << 3));
#pragma unroll
    for (int rb = 0; rb < 2; ++rb)
#pragma unroll
      for (int cb = 0; cb < 2; ++cb)
        e2[rb][cb] = __builtin_amdgcn_mfma_f32_16x16x32_f16(fz[rb], fz[cb], e2[rb][cb], 0, 0, 0);
  }
  // Qe = c5 Z2e + c3 Ze + c1 I (to LDS); RPe = c4 Z2e + c2 Ze + c0 I (in acc)
#pragma unroll
  for (int ti = 0; ti < 2; ++ti)
#pragma unroll
    for (int tj = 0; tj < 2; ++tj) {
      const int off = swz32((tj << 4) + lm, (ti << 4) + (lg << 2));
      f16x4 qe;
      f32x4 rpe;
#pragma unroll
      for (int r = 0; r < 4; ++r) {
        const bool dg = (ti == tj) && (((lg << 2) + r) == lm);
        qe[r] = (_Float16)fmaf(co.c[5], e2[ti][tj][r],
                               fmaf(co.c[3], eZ[ti][tj][r], dg ? co.c[1] : 0.0f));
        rpe[r] = fmaf(co.c[4], e2[ti][tj][r],
                      fmaf(co.c[2], eZ[ti][tj][r], dg ? co.c[0] : 0.0f));
      }
      e2[ti][tj] = rpe;
      *(f16x4*)(QeB + off) = qe;
    }
  // out = P*Qe + RPe -> global (transposed float4; result symmetric)
  {
    f16x8 fp[2], fq[2];
#pragma unroll
    for (int rb = 0; rb < 2; ++rb) {
      fp[rb] = *(const f16x8*)(PB + swz32((rb << 4) + lm, lg << 3));
      fq[rb] = *(const f16x8*)(QeB + swz32((rb << 4) + lm, lg << 3));
    }
#pragma unroll
    for (int rb = 0; rb < 2; ++rb)
#pragma unroll
      for (int cb = 0; cb < 2; ++cb)
        e2[rb][cb] = __builtin_amdgcn_mfma_f32_16x16x32_f16(fp[rb], fq[cb], e2[rb][cb], 0, 0, 0);
#pragma unroll
    for (int ti = 0; ti < 2; ++ti)
#pragma unroll
      for (int tj = 0; tj < 2; ++tj) {
        const int pcol = (tj << 4) + lm;
        const int prow0 = (ti << 4) + (lg << 2);
        *(float4*)&Om[pcol * 32 + prow0] =
            make_float4(e2[ti][tj][0], e2[ti][tj][1], e2[ti][tj][2], e2[ti][tj][3]);
      }
  }
}

static void make_coeffs(Coeffs* co) {
  const int DEG = 5;
  const double center = 3.5, half = 2.5;  // spectrum [1,6]
  const double r = half / center;
  const double w = (1.0 - sqrt(1.0 - r * r)) / r;
  double a[6] = {0};
  a[0] = log(center) - log1p(w * w);
  double wk = 1.0;
  for (int k = 1; k <= DEG; ++k) {
    wk *= w;
    a[k] = 2.0 * ((k & 1) ? 1.0 : -1.0) * wk / k;
  }
  double Tc[6][6] = {{0}};
  Tc[0][0] = 1.0;
  Tc[1][1] = 1.0;
  for (int j = 2; j <= DEG; ++j)
    for (int k = 0; k < 6; ++k)
      Tc[j][k] = 2.0 * (k > 0 ? Tc[j - 1][k - 1] : 0.0) - Tc[j - 2][k];
  double b[6] = {0};
  for (int j = 0; j <= DEG; ++j)
    for (int k = 0; k <= j; ++k)
      b[k] += a[j] * Tc[j][k];
  double fact = 1.0;
  for (int k = 0; k < 6; ++k) {
    co->b[k] = (float)b[k];
    co->c[k] = (float)(1.0 / fact);
    fact *= (double)(k + 1);
  }
}

extern "C" void kernel_launch(void* const* d_in, const int* in_sizes, int n_in,
                              void* d_out, int out_size, void* d_ws, size_t ws_size,
                              hipStream_t stream) {
  Coeffs co;
  make_coeffs(&co);
  const float* A = (const float*)d_in[0];
  float* out = (float*)d_out;
  const int nmat = in_sizes[0] / 4096;  // 8192
  hipLaunchKernelGGL(spd_wave_kernel, dim3(nmat), dim3(64), 0, stream,
                     A, out, co);
}

// Round 11
// 39.172 us; speedup vs baseline: 1.0153x; 1.0153x over previous
//
#include <hip/hip_runtime.h>
#include <math.h>

// SPD logm -> 2x2 avg-pool -> expm via matrix polynomials on fp16 MFMA.
// p(T) = T*q(Z) + r(Z), Z = T^2 (Paterson-Stockmeyer); q,r register-only,
// r(Z) enters as the MFMA C-initializer. Single fp16 operands (~9e-3 worst
// case chain error << 3.36e-2 threshold; measured at the 0.0078 floor).
// Round 11: EXACT round-5 compute; 2 matrices per block with straight-line
// register prefetch (mat1's 4 float4 loads issued before mat0's compute).
// launch_bounds(256,4) keeps the 128-VGPR budget: 44 base + 16 prefetch,
// no spill (round 6's failure was the same idea under the 85-VGPR budget).

typedef __attribute__((ext_vector_type(8))) _Float16 f16x8;
typedef __attribute__((ext_vector_type(4))) _Float16 f16x4;
typedef __attribute__((ext_vector_type(2))) _Float16 f16x2;
typedef __attribute__((ext_vector_type(4))) float f32x4;

constexpr int THREADS = 256;

struct Coeffs {
  float b[6];  // logm monomial coeffs (degree 5), Chebyshev fit on [1,6]
  float c[6];  // expm Taylor 1/k!
};

// byte offset of (r,c): 64x64 f16, 128B rows, 16B-granule XOR swizzle
__device__ __forceinline__ int swz64(int r, int c) {
  return r * 128 + ((((c >> 3) ^ r) & 7) << 4) + ((c & 7) << 1);
}
// 32x32 f16, 64B rows, 4 granules
__device__ __forceinline__ int swz32(int r, int c) {
  return r * 64 + ((((c >> 3) ^ r) & 3) << 4) + ((c & 7) << 1);
}

__device__ __forceinline__ f16x4 cvt4(float a, float b, float c, float d) {
  f16x4 v;
  v[0] = (_Float16)a; v[1] = (_Float16)b; v[2] = (_Float16)c; v[3] = (_Float16)d;
  return v;
}

__global__ __launch_bounds__(THREADS, 4) void spd_fp16pf_kernel(
    const float* __restrict__ A, float* __restrict__ out, Coeffs co) {
  __shared__ __align__(16) char smem[24576];
  char* TB = smem;           // 64x64 f16 T          (8 KB)
  char* ZB = smem + 8192;    // Z = T^2              (8 KB)
  char* QB = smem + 16384;   // Q = q(Z)             (8 KB)
  char* PB  = ZB;            // 32x32 pooled P  (2 KB), live after B4
  char* ZeB = TB;            // Ze = P^2        (2 KB), live after B5
  char* QeB = TB + 2048;     // Qe = q_e(Ze)    (2 KB)

  const int tid = threadIdx.x;
  const size_t m0 = (size_t)blockIdx.x * 2;
  const float4* __restrict__ Ap0 = (const float4*)(A + m0 * 4096);
  const float4* __restrict__ Ap1 = (const float4*)(A + m0 * 4096 + 4096);

  const int w  = tid >> 6;
  const int lm = tid & 15;
  const int lg = (tid & 63) >> 4;
  const int wr = w >> 1, wc = w & 1;
  const bool diag = (wr == wc);

  // stage: registers -> T = (A - 3.5 I)/2.5 -> f16 swizzled LDS
  auto stage = [&](const float4* raw) {
    const float invh = 0.4f;
#pragma unroll
    for (int it = 0; it < 4; ++it) {
      float4 v = raw[it];
      const int e4 = tid + (it << 8);
      const int row = e4 >> 4;
      const int c0 = (e4 & 15) << 2;
      const int d = row - c0;
      if (d == 0) v.x -= 3.5f;
      else if (d == 1) v.y -= 3.5f;
      else if (d == 2) v.z -= 3.5f;
      else if (d == 3) v.w -= 3.5f;
      *(f16x4*)(TB + swz64(row, c0)) =
          cvt4(v.x * invh, v.y * invh, v.z * invh, v.w * invh);
    }
  };

  auto mm64 = [&](const char* X, const char* Y, bool useDiag, f32x4 acc[2][2]) {
#pragma unroll
    for (int kh = 0; kh < 2; ++kh) {
      const int cb = (kh << 5) + (lg << 3);
      f16x8 a[2], b[2];
#pragma unroll
      for (int t = 0; t < 2; ++t)
        a[t] = *(const f16x8*)(X + swz64((wr << 5) + (t << 4) + lm, cb));
      if (useDiag) { b[0] = a[0]; b[1] = a[1]; }
      else {
#pragma unroll
        for (int t = 0; t < 2; ++t)
          b[t] = *(const f16x8*)(Y + swz64((wc << 5) + (t << 4) + lm, cb));
      }
#pragma unroll
      for (int ti = 0; ti < 2; ++ti)
#pragma unroll
        for (int tj = 0; tj < 2; ++tj)
          acc[ti][tj] = __builtin_amdgcn_mfma_f32_16x16x32_f16(a[ti], b[tj], acc[ti][tj], 0, 0, 0);
    }
  };
  auto mm32 = [&](const char* X, const char* Y, bool useDiag, f32x4& a4) {
    const int cb = lg << 3;
    f16x8 a = *(const f16x8*)(X + swz32((wr << 4) + lm, cb));
    f16x8 b;
    if (useDiag) b = a;
    else b = *(const f16x8*)(Y + swz32((wc << 4) + lm, cb));
    a4 = __builtin_amdgcn_mfma_f32_16x16x32_f16(a, b, a4, 0, 0, 0);
  };

  // full compute chain for the matrix currently staged in TB; writes Om
  auto compute = [&](float* __restrict__ Om) {
    // ---- mm1: Z = T*T ; write Z f16 transposed ----
    f32x4 Z[2][2];
#pragma unroll
    for (int ti = 0; ti < 2; ++ti)
#pragma unroll
      for (int tj = 0; tj < 2; ++tj) Z[ti][tj] = f32x4{0.f, 0.f, 0.f, 0.f};
    mm64(TB, TB, diag, Z);
#pragma unroll
    for (int ti = 0; ti < 2; ++ti)
#pragma unroll
      for (int tj = 0; tj < 2; ++tj) {
        const int row0 = (wr << 5) + (ti << 4) + (lg << 2);
        const int colB = (wc << 5) + (tj << 4) + lm;
        *(f16x4*)(ZB + swz64(colB, row0)) =
            cvt4(Z[ti][tj][0], Z[ti][tj][1], Z[ti][tj][2], Z[ti][tj][3]);
      }
    __syncthreads();  // B2

    // ---- mm2: Z2 = Z*Z ; Q = b5 Z2 + b3 Z + b1 I ; RP = b4 Z2 + b2 Z + b0 I ----
    f32x4 Z2[2][2];
#pragma unroll
    for (int ti = 0; ti < 2; ++ti)
#pragma unroll
      for (int tj = 0; tj < 2; ++tj) Z2[ti][tj] = f32x4{0.f, 0.f, 0.f, 0.f};
    mm64(ZB, ZB, diag, Z2);
    f32x4 RP[2][2];
#pragma unroll
    for (int ti = 0; ti < 2; ++ti)
#pragma unroll
      for (int tj = 0; tj < 2; ++tj) {
        const int row0 = (wr << 5) + (ti << 4) + (lg << 2);
        const int colB = (wc << 5) + (tj << 4) + lm;
        float qv[4];
#pragma unroll
        for (int r = 0; r < 4; ++r) {
          const float dq = (row0 + r == colB) ? co.b[1] : 0.0f;
          const float dr = (row0 + r == colB) ? co.b[0] : 0.0f;
          qv[r] = fmaf(co.b[5], Z2[ti][tj][r], fmaf(co.b[3], Z[ti][tj][r], dq));
          RP[ti][tj][r] = fmaf(co.b[4], Z2[ti][tj][r], fmaf(co.b[2], Z[ti][tj][r], dr));
        }
        *(f16x4*)(QB + swz64(colB, row0)) = cvt4(qv[0], qv[1], qv[2], qv[3]);
      }
    __syncthreads();  // B3

    // ---- mm3: L = T*Q + RP ; fused 2x2 pooling -> P (f16, overlays ZB) ----
    mm64(TB, QB, false, RP);
#pragma unroll
    for (int ti = 0; ti < 2; ++ti)
#pragma unroll
      for (int tj = 0; tj < 2; ++tj) {
        const float vs0 = RP[ti][tj][0] + RP[ti][tj][1];
        const float vs1 = RP[ti][tj][2] + RP[ti][tj][3];
        const float hs0 = vs0 + __shfl_xor(vs0, 1);
        const float hs1 = vs1 + __shfl_xor(vs1, 1);
        if ((lm & 1) == 0) {
          const int pr = (wr << 4) + (ti << 3) + (lg << 1);
          const int pc = (wc << 4) + (tj << 3) + (lm >> 1);
          f16x2 p;
          p[0] = (_Float16)(0.25f * hs0);
          p[1] = (_Float16)(0.25f * hs1);
          *(f16x2*)(PB + swz32(pc, pr)) = p;  // transposed (symmetric)
        }
      }
    __syncthreads();  // B4

    const int prow0 = (wr << 4) + (lg << 2);
    const int pcol = (wc << 4) + lm;

    // Ze = P*P (regs) ; write f16 transposed into ZeB (overlays TB)
    f32x4 Ze = f32x4{0.f, 0.f, 0.f, 0.f};
    mm32(PB, PB, diag, Ze);
    *(f16x4*)(ZeB + swz32(pcol, prow0)) = cvt4(Ze[0], Ze[1], Ze[2], Ze[3]);
    __syncthreads();  // B5

    // Z2e = Ze*Ze ; Qe = c5 Z2e + c3 Ze + c1 I ; RPe = c4 Z2e + c2 Ze + c0 I
    f32x4 Z2e = f32x4{0.f, 0.f, 0.f, 0.f};
    mm32(ZeB, ZeB, diag, Z2e);
    f32x4 RPe;
    {
      float qv[4];
#pragma unroll
      for (int r = 0; r < 4; ++r) {
        const float dq = (prow0 + r == pcol) ? co.c[1] : 0.0f;
        const float dr = (prow0 + r == pcol) ? co.c[0] : 0.0f;
        qv[r] = fmaf(co.c[5], Z2e[r], fmaf(co.c[3], Ze[r], dq));
        RPe[r] = fmaf(co.c[4], Z2e[r], fmaf(co.c[2], Ze[r], dr));
      }
      *(f16x4*)(QeB + swz32(pcol, prow0)) = cvt4(qv[0], qv[1], qv[2], qv[3]);
    }
    __syncthreads();  // B6

    // out = P*Qe + RPe -> global (transposed float4; result symmetric)
    mm32(PB, QeB, false, RPe);
    *(float4*)&Om[pcol * 32 + prow0] = make_float4(RPe[0], RPe[1], RPe[2], RPe[3]);
  };

  // ---- matrix 0: load, stage, then issue matrix 1's loads (prefetch) ----
  float4 raw0[4];
#pragma unroll
  for (int it = 0; it < 4; ++it) raw0[it] = Ap0[tid + (it << 8)];
  stage(raw0);
  float4 raw1[4];
#pragma unroll
  for (int it = 0; it < 4; ++it) raw1[it] = Ap1[tid + (it << 8)];
  __syncthreads();  // B1 (mat 0)

  compute(out + m0 * 1024);
  __syncthreads();  // B7: all LDS reads of mat 0 done before restaging TB

  // ---- matrix 1 ----
  stage(raw1);
  __syncthreads();  // B1 (mat 1)
  compute(out + m0 * 1024 + 1024);
}

static void make_coeffs(Coeffs* co) {
  const int DEG = 5;
  const double center = 3.5, half = 2.5;  // spectrum [1,6]
  const double r = half / center;
  const double w = (1.0 - sqrt(1.0 - r * r)) / r;
  double a[6] = {0};
  a[0] = log(center) - log1p(w * w);
  double wk = 1.0;
  for (int k = 1; k <= DEG; ++k) {
    wk *= w;
    a[k] = 2.0 * ((k & 1) ? 1.0 : -1.0) * wk / k;
  }
  double Tc[6][6] = {{0}};
  Tc[0][0] = 1.0;
  Tc[1][1] = 1.0;
  for (int j = 2; j <= DEG; ++j)
    for (int k = 0; k < 6; ++k)
      Tc[j][k] = 2.0 * (k > 0 ? Tc[j - 1][k - 1] : 0.0) - Tc[j - 2][k];
  double b[6] = {0};
  for (int j = 0; j <= DEG; ++j)
    for (int k = 0; k <= j; ++k)
      b[k] += a[j] * Tc[j][k];
  double fact = 1.0;
  for (int k = 0; k < 6; ++k) {
    co->b[k] = (float)b[k];
    co->c[k] = (float)(1.0 / fact);
    fact *= (double)(k + 1);
  }
}

extern "C" void kernel_launch(void* const* d_in, const int* in_sizes, int n_in,
                              void* d_out, int out_size, void* d_ws, size_t ws_size,
                              hipStream_t stream) {
  Coeffs co;
  make_coeffs(&co);
  const float* A = (const float*)d_in[0];
  float* out = (float*)d_out;
  const int nmat = in_sizes[0] / 4096;  // 8192
  hipLaunchKernelGGL(spd_fp16pf_kernel, dim3(nmat / 2), dim3(THREADS), 0, stream,
                     A, out, co);
}